// Round 7
// baseline (211.983 us; speedup 1.0000x reference)
//
#include <hip/hip_runtime.h>

#define NN 24
#define POWER_ITERS 30
#define FISTA_ITERS 200

// 8-lane-group broadcast: every lane reads the value held by lane (group_base | ML).
// ds_swizzle BitMode offset = (xor<<10)|(or<<5)|and ; and=0x18 keeps the 8-group base.
template<int ML>
__device__ __forceinline__ float bc8(float v) {
    return __int_as_float(__builtin_amdgcn_ds_swizzle(__float_as_int(v), (ML << 5) | 0x18));
}
// XOR butterflies for 8-lane reductions
__device__ __forceinline__ float gx1(float v) {
    return __int_as_float(__builtin_amdgcn_ds_swizzle(__float_as_int(v), 0x041F));
}
__device__ __forceinline__ float gx2(float v) {
    return __int_as_float(__builtin_amdgcn_ds_swizzle(__float_as_int(v), 0x081F));
}
__device__ __forceinline__ float gx4(float v) {
    return __int_as_float(__builtin_amdgcn_ds_swizzle(__float_as_int(v), 0x101F));
}

// Fused all-gather + matvec, swizzle-only, SCALAR v_fma form.
// Distribution: y[j] j<8 -> lane j slot s0 ; y[8+2c+e] -> lane c slot s1/s2.
// Scalar v_fma_f32 can source AGPRs directly on CDNA, so wherever the
// allocator puts G rows, no accvgpr/packing moves are needed (unlike VOP3P
// v_pk_fma_f32, which wants aligned VGPR pairs — measured +~95 moves/iter
// in rounds 5/6).
#define MV(j, bexpr) { const float vj = (bexpr);                               \
    g0 = fmaf(G0[j], vj, g0); g1 = fmaf(G1[j], vj, g1); g2 = fmaf(G2[j], vj, g2); }
#define MATVEC_SWZ(s0, s1, s2, g0, g1, g2) do {                                \
    MV(0,  bc8<0>(s0)) MV(1,  bc8<1>(s0)) MV(2,  bc8<2>(s0)) MV(3,  bc8<3>(s0)) \
    MV(4,  bc8<4>(s0)) MV(5,  bc8<5>(s0)) MV(6,  bc8<6>(s0)) MV(7,  bc8<7>(s0)) \
    MV(8,  bc8<0>(s1)) MV(9,  bc8<0>(s2)) MV(10, bc8<1>(s1)) MV(11, bc8<1>(s2)) \
    MV(12, bc8<2>(s1)) MV(13, bc8<2>(s2)) MV(14, bc8<3>(s1)) MV(15, bc8<3>(s2)) \
    MV(16, bc8<4>(s1)) MV(17, bc8<4>(s2)) MV(18, bc8<5>(s1)) MV(19, bc8<5>(s2)) \
    MV(20, bc8<6>(s1)) MV(21, bc8<6>(s2)) MV(22, bc8<7>(s1)) MV(23, bc8<7>(s2)) \
} while (0)

// __launch_bounds__(256, 2): 2nd arg is min waves per EU on AMD -> 256-reg
// budget per wave; the whole state (~110 floats) fits in arch VGPRs with no
// spills. Occupancy target 2 waves/SIMD matches what we measured anyway
// (2.1-2.65) while halving the instruction stream.
__global__ __attribute__((amdgpu_waves_per_eu(2, 2))) void __launch_bounds__(256, 2)
qcqp_kernel(const float* __restrict__ P, const float* __restrict__ qv,
            float* __restrict__ out, int Btot) {
    const int tid = blockIdx.x * blockDim.x + threadIdx.x;
    const int b = tid >> 3;
    if (b >= Btot) return;
    const int ls = tid & 7;       // lane-in-group; owns cone ls
    const int rx = 8 + 2 * ls;    // global rows {ls, rx, rx+1}

    const float* __restrict__ Pb = P + (size_t)b * (NN * NN);
    const float* __restrict__ qb = qv + (size_t)b * NN;

    // ---- Phase 1: own 3 rows of G = P^T P (REG=1e-7 dropped: ~3e-8 rel),
    //      bb = -(P^T q) own rows ----
    float G0[NN], G1[NN], G2[NN];
#pragma unroll
    for (int j = 0; j < NN; ++j) { G0[j] = 0.f; G1[j] = 0.f; G2[j] = 0.f; }
    float bb0 = 0.f, bb1 = 0.f, bb2 = 0.f;

#pragma unroll 1
    for (int k = 0; k < NN; ++k) {
        const float* rp = Pb + k * NN;
        float row[NN];
#pragma unroll
        for (int m = 0; m < 6; ++m) {
            const float4 r = *reinterpret_cast<const float4*>(rp + 4 * m);
            row[4 * m + 0] = r.x;
            row[4 * m + 1] = r.y;
            row[4 * m + 2] = r.z;
            row[4 * m + 3] = r.w;
        }
        const float  a0 = rp[ls];
        const float2 ax = *reinterpret_cast<const float2*>(rp + rx);
        const float  qk = qb[k];
        bb0 = fmaf(-a0,   qk, bb0);
        bb1 = fmaf(-ax.x, qk, bb1);
        bb2 = fmaf(-ax.y, qk, bb2);
#pragma unroll
        for (int j = 0; j < NN; ++j) {
            G0[j] = fmaf(a0,   row[j], G0[j]);
            G1[j] = fmaf(ax.x, row[j], G1[j]);
            G2[j] = fmaf(ax.y, row[j], G2[j]);
        }
    }

    // ---- Phase 2: power iteration -> step = 1/(L + 1e-12) ----
    float vo0 = 0.20412414523193150818f;  // 1/sqrt(24)
    float vo1 = vo0, vo2 = vo0;

#pragma unroll 1
    for (int it = 0; it < POWER_ITERS; ++it) {
        float g0 = 0.f, g1 = 0.f, g2 = 0.f;
        MATVEC_SWZ(vo0, vo1, vo2, g0, g1, g2);
        float n2 = g0 * g0 + g1 * g1 + g2 * g2;
        n2 += gx1(n2);
        n2 += gx2(n2);
        n2 += gx4(n2);
        const float inv = __builtin_amdgcn_rsqf(fmaxf(n2, 1e-60f));
        vo0 = g0 * inv; vo1 = g1 * inv; vo2 = g2 * inv;
    }
    float step;
    {
        float g0 = 0.f, g1 = 0.f, g2 = 0.f;
        MATVEC_SWZ(vo0, vo1, vo2, g0, g1, g2);
        float Lp = vo0 * g0 + vo1 * g1 + vo2 * g2;
        Lp += gx1(Lp);
        Lp += gx2(Lp);
        Lp += gx4(Lp);
        step = __builtin_amdgcn_rcpf(Lp + 1e-12f);
    }
    const float nstep = -step;

    // ---- Phase 3: FISTA ----
    float yo0 = 0.f, yo1 = 0.f, yo2 = 0.f;
    float lo0 = 0.f, lo1 = 0.f, lo2 = 0.f;
    float tk = 1.f;

#pragma unroll 1
    for (int it = 0; it < FISTA_ITERS; ++it) {
        float g0 = bb0, g1 = bb1, g2 = bb2;
        MATVEC_SWZ(yo0, yo1, yo2, g0, g1, g2);
        const float t  = fmaf(nstep, g0, yo0);
        const float x1 = fmaf(nstep, g1, yo1);
        const float x2 = fmaf(nstep, g2, yo2);
        // SOC projection (lane-local: lane owns exactly cone ls)
        const float nx    = __builtin_amdgcn_sqrtf(fmaf(x1, x1, x2 * x2));
        const float alpha = 0.5f * (t + nx);
        const bool inside = (nx <= t);
        const bool zero_  = (nx <= -t);
        const float ln0 = inside ? t : (zero_ ? 0.f : alpha);
        const float sc  = inside ? 1.f
                                 : (zero_ ? 0.f
                                          : alpha * __builtin_amdgcn_rcpf(fmaxf(nx, 1e-12f)));
        const float ln1 = x1 * sc;
        const float ln2 = x2 * sc;
        const float tkn = 0.5f * (1.f + __builtin_amdgcn_sqrtf(fmaf(4.f * tk, tk, 1.f)));
        const float bet = (tk - 1.f) * __builtin_amdgcn_rcpf(tkn);
        tk = tkn;
        yo0 = fmaf(bet, ln0 - lo0, ln0);
        yo1 = fmaf(bet, ln1 - lo1, ln1);
        yo2 = fmaf(bet, ln2 - lo2, ln2);
        lo0 = ln0; lo1 = ln1; lo2 = ln2;
    }

    // ---- store own components (disjoint across the group, covers all 24) ----
    float* ob = out + (size_t)b * NN;
    ob[ls] = lo0;
    *reinterpret_cast<float2*>(ob + rx) = make_float2(lo1, lo2);
}

extern "C" void kernel_launch(void* const* d_in, const int* in_sizes, int n_in,
                              void* d_out, int out_size, void* d_ws, size_t ws_size,
                              hipStream_t stream) {
    const float* P = (const float*)d_in[0];
    const float* q = (const float*)d_in[1];
    float* out = (float*)d_out;
    const int Btot = in_sizes[0] / (NN * NN);
    const long long threads = 8LL * Btot;
    const int block = 256;
    const int grid = (int)((threads + block - 1) / block);
    qcqp_kernel<<<grid, block, 0, stream>>>(P, q, out, Btot);
}

// Round 8
// 147.228 us; speedup vs baseline: 1.4398x; 1.4398x over previous
//
#include <hip/hip_runtime.h>

#define NN 24
#define POWER_ITERS 30
#define FISTA_ITERS 200

// Quad-lane (4-lane group) cross-lane ops via DPP — VALU pipe, NOT the DS
// pipe. Rounds 5-7 were bound by ds_swizzle throughput (~24 DS/iter/wave,
// ~88k DS-instr/CU ≈ 440-510k cycles ≈ the measured 181-212 µs). quad_perm
// DPP broadcasts cost a VALU slot instead, and the VALU has headroom.
template<int CTRL>
__device__ __forceinline__ float dpp4(float v) {
    return __int_as_float(__builtin_amdgcn_update_dpp(
        0, __float_as_int(v), CTRL, 0xF, 0xF, true));
}
// broadcast lane L of each quad: quad_perm[L,L,L,L] = L*0x55
#define BC0(x) dpp4<0x00>(x)
#define BC1(x) dpp4<0x55>(x)
#define BC2(x) dpp4<0xAA>(x)
#define BC3(x) dpp4<0xFF>(x)
// quad butterflies: xor1 = quad_perm[1,0,3,2] = 0xB1 ; xor2 = quad_perm[2,3,0,1] = 0x4E
#define QX1(x) dpp4<0xB1>(x)
#define QX2(x) dpp4<0x4E>(x)

// Lane q (=tid&3) owns cones {2q, 2q+1}: rows {2q, 2q+1, 8+4q..11+4q}.
// y slots: s0=y[2q] s1=y[2q+1] s2=y[8+4q] s3=y[9+4q] s4=y[10+4q] s5=y[11+4q].
// Full-vector element j -> (owner lane, slot):
//   j<8: lane j>>1, slot j&1 ; j>=8: lane (j-8)>>2, slot 2+((j-8)&3).
#define MV6(j, e) { const float vj = (e);                                      \
    g0 = fmaf(GR0[j], vj, g0); g1 = fmaf(GR1[j], vj, g1);                      \
    g2 = fmaf(GR2[j], vj, g2); g3 = fmaf(GR3[j], vj, g3);                      \
    g4 = fmaf(GR4[j], vj, g4); g5 = fmaf(GR5[j], vj, g5); }
#define MATVEC_DPP(s0, s1, s2, s3, s4, s5) do {                                \
    MV6(0,  BC0(s0)) MV6(1,  BC0(s1)) MV6(2,  BC1(s0)) MV6(3,  BC1(s1))       \
    MV6(4,  BC2(s0)) MV6(5,  BC2(s1)) MV6(6,  BC3(s0)) MV6(7,  BC3(s1))       \
    MV6(8,  BC0(s2)) MV6(9,  BC0(s3)) MV6(10, BC0(s4)) MV6(11, BC0(s5))       \
    MV6(12, BC1(s2)) MV6(13, BC1(s3)) MV6(14, BC1(s4)) MV6(15, BC1(s5))       \
    MV6(16, BC2(s2)) MV6(17, BC2(s3)) MV6(18, BC2(s4)) MV6(19, BC2(s5))       \
    MV6(20, BC3(s2)) MV6(21, BC3(s3)) MV6(22, BC3(s4)) MV6(23, BC3(s5))       \
} while (0)

// waves_per_eu(1,2) + launch_bounds(256,1): allow a 1-wave/EU register budget
// (up to 512 unified regs) so G (144 floats) + state can live in arch VGPRs.
// The main loops are pure register math (DPP+FMA, no memory), so even
// occupancy 1 is latency-tolerant: 6 independent FMA chains cover DPP latency.
__global__ __attribute__((amdgpu_waves_per_eu(1, 2))) void __launch_bounds__(256, 1)
qcqp_kernel(const float* __restrict__ P, const float* __restrict__ qv,
            float* __restrict__ out, int Btot) {
    const int tid = blockIdx.x * blockDim.x + threadIdx.x;
    const int b = tid >> 2;
    if (b >= Btot) return;
    const int q = tid & 3;         // lane-in-quad; owns cones 2q, 2q+1
    const int rt = 2 * q;          // t rows: rt, rt+1
    const int rx = 8 + 4 * q;      // x rows: rx .. rx+3

    const float* __restrict__ Pb = P + (size_t)b * (NN * NN);
    const float* __restrict__ qb = qv + (size_t)b * NN;

    // ---- Phase 1: own 6 rows of G = P^T P (REG=1e-7 dropped: ~3e-8 rel),
    //      bb = -(P^T q) own rows ----
    float GR0[NN], GR1[NN], GR2[NN], GR3[NN], GR4[NN], GR5[NN];
#pragma unroll
    for (int j = 0; j < NN; ++j) {
        GR0[j] = 0.f; GR1[j] = 0.f; GR2[j] = 0.f;
        GR3[j] = 0.f; GR4[j] = 0.f; GR5[j] = 0.f;
    }
    float bb0 = 0.f, bb1 = 0.f, bb2 = 0.f, bb3 = 0.f, bb4 = 0.f, bb5 = 0.f;

#pragma unroll 1
    for (int k = 0; k < NN; ++k) {
        const float* rp = Pb + k * NN;
        float row[NN];
#pragma unroll
        for (int m = 0; m < 6; ++m) {
            const float4 r = *reinterpret_cast<const float4*>(rp + 4 * m);
            row[4 * m + 0] = r.x;
            row[4 * m + 1] = r.y;
            row[4 * m + 2] = r.z;
            row[4 * m + 3] = r.w;
        }
        const float2 at = *reinterpret_cast<const float2*>(rp + rt);  // 8B aligned
        const float4 axv = *reinterpret_cast<const float4*>(rp + rx); // 16B aligned
        const float qk = qb[k];
        bb0 = fmaf(-at.x,  qk, bb0);
        bb1 = fmaf(-at.y,  qk, bb1);
        bb2 = fmaf(-axv.x, qk, bb2);
        bb3 = fmaf(-axv.y, qk, bb3);
        bb4 = fmaf(-axv.z, qk, bb4);
        bb5 = fmaf(-axv.w, qk, bb5);
#pragma unroll
        for (int j = 0; j < NN; ++j) {
            GR0[j] = fmaf(at.x,  row[j], GR0[j]);
            GR1[j] = fmaf(at.y,  row[j], GR1[j]);
            GR2[j] = fmaf(axv.x, row[j], GR2[j]);
            GR3[j] = fmaf(axv.y, row[j], GR3[j]);
            GR4[j] = fmaf(axv.z, row[j], GR4[j]);
            GR5[j] = fmaf(axv.w, row[j], GR5[j]);
        }
    }

    // ---- Phase 2: power iteration -> step = 1/(L + 1e-12) ----
    float vo0 = 0.20412414523193150818f;  // 1/sqrt(24)
    float vo1 = vo0, vo2 = vo0, vo3 = vo0, vo4 = vo0, vo5 = vo0;

#pragma unroll 1
    for (int it = 0; it < POWER_ITERS; ++it) {
        float g0 = 0.f, g1 = 0.f, g2 = 0.f, g3 = 0.f, g4 = 0.f, g5 = 0.f;
        MATVEC_DPP(vo0, vo1, vo2, vo3, vo4, vo5);
        float n2 = g0 * g0 + g1 * g1 + g2 * g2 + g3 * g3 + g4 * g4 + g5 * g5;
        n2 += QX1(n2);
        n2 += QX2(n2);
        const float inv = __builtin_amdgcn_rsqf(fmaxf(n2, 1e-60f));
        vo0 = g0 * inv; vo1 = g1 * inv; vo2 = g2 * inv;
        vo3 = g3 * inv; vo4 = g4 * inv; vo5 = g5 * inv;
    }
    float step;
    {
        float g0 = 0.f, g1 = 0.f, g2 = 0.f, g3 = 0.f, g4 = 0.f, g5 = 0.f;
        MATVEC_DPP(vo0, vo1, vo2, vo3, vo4, vo5);
        float Lp = vo0 * g0 + vo1 * g1 + vo2 * g2 + vo3 * g3 + vo4 * g4 + vo5 * g5;
        Lp += QX1(Lp);
        Lp += QX2(Lp);
        step = __builtin_amdgcn_rcpf(Lp + 1e-12f);
    }
    const float nstep = -step;

    // ---- Phase 3: FISTA ----
    float yo0 = 0.f, yo1 = 0.f, yo2 = 0.f, yo3 = 0.f, yo4 = 0.f, yo5 = 0.f;
    float lo0 = 0.f, lo1 = 0.f, lo2 = 0.f, lo3 = 0.f, lo4 = 0.f, lo5 = 0.f;
    float tk = 1.f;

#pragma unroll 1
    for (int it = 0; it < FISTA_ITERS; ++it) {
        float g0 = bb0, g1 = bb1, g2 = bb2, g3 = bb3, g4 = bb4, g5 = bb5;
        MATVEC_DPP(yo0, yo1, yo2, yo3, yo4, yo5);
        const float tA  = fmaf(nstep, g0, yo0);
        const float tB  = fmaf(nstep, g1, yo1);
        const float xA1 = fmaf(nstep, g2, yo2);
        const float xA2 = fmaf(nstep, g3, yo3);
        const float xB1 = fmaf(nstep, g4, yo4);
        const float xB2 = fmaf(nstep, g5, yo5);
        // SOC projection, cone A = (tA; xA1, xA2), cone B = (tB; xB1, xB2)
        const float nxA = __builtin_amdgcn_sqrtf(fmaf(xA1, xA1, xA2 * xA2));
        const float nxB = __builtin_amdgcn_sqrtf(fmaf(xB1, xB1, xB2 * xB2));
        const float alA = 0.5f * (tA + nxA);
        const float alB = 0.5f * (tB + nxB);
        const bool inA = (nxA <= tA), zA = (nxA <= -tA);
        const bool inB = (nxB <= tB), zB = (nxB <= -tB);
        const float lnA0 = inA ? tA : (zA ? 0.f : alA);
        const float lnB0 = inB ? tB : (zB ? 0.f : alB);
        const float scA = inA ? 1.f
                              : (zA ? 0.f : alA * __builtin_amdgcn_rcpf(fmaxf(nxA, 1e-12f)));
        const float scB = inB ? 1.f
                              : (zB ? 0.f : alB * __builtin_amdgcn_rcpf(fmaxf(nxB, 1e-12f)));
        const float lnA1 = xA1 * scA, lnA2 = xA2 * scA;
        const float lnB1 = xB1 * scB, lnB2 = xB2 * scB;
        const float tkn = 0.5f * (1.f + __builtin_amdgcn_sqrtf(fmaf(4.f * tk, tk, 1.f)));
        const float bet = (tk - 1.f) * __builtin_amdgcn_rcpf(tkn);
        tk = tkn;
        yo0 = fmaf(bet, lnA0 - lo0, lnA0); lo0 = lnA0;
        yo1 = fmaf(bet, lnB0 - lo1, lnB0); lo1 = lnB0;
        yo2 = fmaf(bet, lnA1 - lo2, lnA1); lo2 = lnA1;
        yo3 = fmaf(bet, lnA2 - lo3, lnA2); lo3 = lnA2;
        yo4 = fmaf(bet, lnB1 - lo4, lnB1); lo4 = lnB1;
        yo5 = fmaf(bet, lnB2 - lo5, lnB2); lo5 = lnB2;
    }

    // ---- store own components (disjoint across the quad, covers all 24) ----
    float* ob = out + (size_t)b * NN;
    *reinterpret_cast<float2*>(ob + rt) = make_float2(lo0, lo1);
    *reinterpret_cast<float4*>(ob + rx) = make_float4(lo2, lo3, lo4, lo5);
}

extern "C" void kernel_launch(void* const* d_in, const int* in_sizes, int n_in,
                              void* d_out, int out_size, void* d_ws, size_t ws_size,
                              hipStream_t stream) {
    const float* P = (const float*)d_in[0];
    const float* q = (const float*)d_in[1];
    float* out = (float*)d_out;
    const int Btot = in_sizes[0] / (NN * NN);
    const long long threads = 4LL * Btot;
    const int block = 256;
    const int grid = (int)((threads + block - 1) / block);
    qcqp_kernel<<<grid, block, 0, stream>>>(P, q, out, Btot);
}